// Round 1
// baseline (13781.438 us; speedup 1.0000x reference)
//
#include <hip/hip_runtime.h>
#include <hip/hip_bf16.h>

#define B_DIM 256
#define T_DIM 512
#define IN_DIM 1024
#define HID_DIM 1024

typedef __attribute__((ext_vector_type(8))) short bf16x8;
typedef __attribute__((ext_vector_type(4))) float f32x4;

__device__ __forceinline__ unsigned short f2bf(float v) {
  unsigned int u = __float_as_uint(v);
  unsigned int r = (u + 0x7fffu + ((u >> 16) & 1u)) >> 16;
  return (unsigned short)r;
}

typedef __attribute__((address_space(3))) unsigned int lds_uint;
typedef const __attribute__((address_space(1))) unsigned int g_uint;
__device__ __forceinline__ void gload_lds16(const void* g, void* l) {
  __builtin_amdgcn_global_load_lds((g_uint*)g, (lds_uint*)l, 16, 0, 0);
}

// ---------------------------------------------------------------------------
// Pack W (4 gates, f32 [2048][1024]) into bf16 blocks ready for linear
// global_load_lds staging. Packed col within a 64-col block: g*16 + h_in
// (g: 0=i,1=f,2=o,3=g). Block (cb, kc) = 16 KB holding cols cb*64.. (as
// [col 64][k' 128] bf16) for k = kc*128.., byte-swizzled:
//   byte = (col*256 + k'*2) ^ ((col&7)<<4)
// ---------------------------------------------------------------------------
__global__ void prep_pack_w(const float* __restrict__ Wi, const float* __restrict__ Wf,
                            const float* __restrict__ Wo, const float* __restrict__ Wc,
                            unsigned char* __restrict__ Wp) {
  const int bid = blockIdx.x;          // 1024 blocks: cb*16 + kc
  const int cb = bid >> 4, kc = bid & 15;
  const int tid = threadIdx.x;
  const int col = tid & 63;            // packed col: g*16 + h_in
  const int g = col >> 4, h_in = col & 15;
  const int kq = tid >> 6;             // quarter of the 128 k's
  const float* W = (g == 0) ? Wi : (g == 1) ? Wf : (g == 2) ? Wo : Wc;
  const float* src = W + (size_t)(kc * 128 + kq * 32) * HID_DIM + cb * 16 + h_in;
  unsigned char* dst = Wp + (size_t)bid * 16384;
  const unsigned int xo = (unsigned int)((col & 7) << 4);
#pragma unroll
  for (int b4 = 0; b4 < 4; ++b4) {
    unsigned short u[8];
#pragma unroll
    for (int j = 0; j < 8; ++j)
      u[j] = f2bf(src[(size_t)(b4 * 8 + j) * HID_DIM]);
    uint4 pk;
    pk.x = (unsigned)u[0] | ((unsigned)u[1] << 16);
    pk.y = (unsigned)u[2] | ((unsigned)u[3] << 16);
    pk.z = (unsigned)u[4] | ((unsigned)u[5] << 16);
    pk.w = (unsigned)u[6] | ((unsigned)u[7] << 16);
    unsigned int byte = ((unsigned int)(col * 256 + kq * 64 + b4 * 16)) ^ xo;
    *(uint4*)(dst + byte) = pk;
  }
}

__global__ void prep_bias(const float* __restrict__ bi, const float* __restrict__ bf_,
                          const float* __restrict__ bo, const float* __restrict__ bc,
                          float* __restrict__ bp) {
  int p = blockIdx.x * 256 + threadIdx.x;  // 0..4095
  int cbb = p >> 6, col = p & 63, g = col >> 4, h_in = col & 15;
  const float* b = (g == 0) ? bi : (g == 1) ? bf_ : (g == 2) ? bo : bc;
  bp[p] = b[cbb * 16 + h_in];
}

// ---------------------------------------------------------------------------
// One LSTM timestep. Grid 256 (one WG/CU), block 256 (4 waves).
// WG (mb, cb): batch rows mb*64..+64, hid cols cb*16..+16 (x4 gates = 64
// packed cols). Fused GEMM: gates[64x64] = [x_t | h] (K=2048) @ Wslice.
// h is carried between launches as a bf16 "LDS image" (same swizzled block
// layout as Wp) so staging is pure global_load_lds. c stays f32 in global.
// ---------------------------------------------------------------------------
__global__ __launch_bounds__(256) void lstm_step(
    const float* __restrict__ x, const unsigned char* __restrict__ Wp,
    const float* __restrict__ bp, const unsigned char* __restrict__ hin,
    unsigned char* __restrict__ hout, float* __restrict__ cst,
    float* __restrict__ out, int t) {
  __shared__ unsigned char smem[65536];  // [A0 16K][B0 16K][A1 16K][B1 16K]
  const int wg = blockIdx.x, mb = wg >> 6, cb = wg & 63;
  const int tid = threadIdx.x, lane = tid & 63, w = tid >> 6;
  const int NC = (t == 0) ? 8 : 16;      // t==0: h==0, skip h-part chunks

  f32x4 acc[2][2] = {{{0.f,0.f,0.f,0.f},{0.f,0.f,0.f,0.f}},
                     {{0.f,0.f,0.f,0.f},{0.f,0.f,0.f,0.f}}};

  // ----- staging -----
  const int xrow = tid >> 2, kseg = tid & 3;
  const float* xbase = x + ((size_t)(mb * 64 + xrow) * T_DIM + t) * IN_DIM + kseg * 32;
  float4 fx[8];

  auto issueX = [&](int kc) {            // load 32 f32 of x into regs (T14 split)
    const float4* s = (const float4*)(xbase + kc * 128);
#pragma unroll
    for (int v = 0; v < 8; ++v) fx[v] = s[v];
  };
  auto writeX = [&](int q) {             // cvt + swizzled ds_write
    unsigned char* Ab = smem + q * 32768;
    const unsigned int base = (unsigned int)(xrow * 256 + kseg * 64);
    const unsigned int xo = (unsigned int)((xrow & 7) << 4);
#pragma unroll
    for (int c4 = 0; c4 < 4; ++c4) {
      const float* f = (const float*)&fx[c4 * 2];
      uint4 pk;
      pk.x = (unsigned)f2bf(f[0]) | ((unsigned)f2bf(f[1]) << 16);
      pk.y = (unsigned)f2bf(f[2]) | ((unsigned)f2bf(f[3]) << 16);
      pk.z = (unsigned)f2bf(f[4]) | ((unsigned)f2bf(f[5]) << 16);
      pk.w = (unsigned)f2bf(f[6]) | ((unsigned)f2bf(f[7]) << 16);
      *(uint4*)(Ab + ((base + c4 * 16) ^ xo)) = pk;
    }
  };
  auto issueH = [&](int kc, int q) {     // h image: direct global->LDS, linear
    const unsigned char* s = hin + ((size_t)(mb * 8 + (kc - 8))) * 16384 + w * 4096 + lane * 16;
    unsigned char* d = smem + q * 32768 + w * 4096;
#pragma unroll
    for (int i = 0; i < 4; ++i) gload_lds16(s + i * 1024, d + i * 1024);
  };
  auto issueB = [&](int kc, int q) {     // weight block: direct global->LDS
    const unsigned char* s = Wp + ((size_t)(cb * 16 + kc)) * 16384 + w * 4096 + lane * 16;
    unsigned char* d = smem + q * 32768 + 16384 + w * 4096;
#pragma unroll
    for (int i = 0; i < 4; ++i) gload_lds16(s + i * 1024, d + i * 1024);
  };

  // ----- MFMA consume -----
  const int wr = w >> 1, wc = w & 1;     // 2x2 wave split of the 64x64 tile
  const int fr = lane & 15, koff = (lane >> 4) * 8;
  auto consume = [&](int q) {
    const unsigned char* Ab = smem + q * 32768;
    const unsigned char* Bb = Ab + 16384;
#pragma unroll
    for (int ks = 0; ks < 4; ++ks) {
      const unsigned int kb2 = (unsigned)(ks * 32 + koff) * 2;
      bf16x8 a[2], b[2];
#pragma unroll
      for (int m = 0; m < 2; ++m) {
        unsigned int row = (unsigned)(wr * 32 + m * 16 + fr);
        a[m] = *(const bf16x8*)(Ab + ((row * 256 + kb2) ^ ((row & 7) << 4)));
      }
#pragma unroll
      for (int n = 0; n < 2; ++n) {
        unsigned int col = (unsigned)(wc * 32 + n * 16 + fr);
        b[n] = *(const bf16x8*)(Bb + ((col * 256 + kb2) ^ ((col & 7) << 4)));
      }
#pragma unroll
      for (int m = 0; m < 2; ++m)
#pragma unroll
        for (int n = 0; n < 2; ++n)
          acc[m][n] = __builtin_amdgcn_mfma_f32_16x16x32_bf16(a[m], b[n], acc[m][n], 0, 0, 0);
    }
  };

  // prologue: chunk 0 (x-part)
  issueX(0); issueB(0, 0); writeX(0);
  __syncthreads();
  for (int kc = 0; kc < NC; ++kc) {
    const int q = kc & 1, qn = q ^ 1;
    const bool more = (kc + 1 < NC);
    const bool nx = more && (kc + 1 < 8);
    if (more) {
      issueB(kc + 1, qn);
      if (nx) issueX(kc + 1); else issueH(kc + 1, qn);
    }
    consume(q);
    if (nx) writeX(qn);
    __syncthreads();
  }

  // ----- gate exchange + elementwise -----
  float* gates = (float*)smem;  // 64x64 f32 overlay on buf0 (consumed & barriered)
#pragma unroll
  for (int m = 0; m < 2; ++m)
#pragma unroll
    for (int n = 0; n < 2; ++n)
#pragma unroll
      for (int j = 0; j < 4; ++j) {
        int row = wr * 32 + m * 16 + (lane >> 4) * 4 + j;
        int col = wc * 32 + n * 16 + fr;
        gates[row * 64 + col] = acc[m][n][j];
      }
  __syncthreads();
  {
    const int row = tid & 63, hsel = tid >> 6;
    const int hb = hsel * 4;
    const size_t gidx = (size_t)(mb * 64 + row) * HID_DIM + cb * 16 + hb;
    float cold[4] = {0.f, 0.f, 0.f, 0.f};
    if (t > 0) *(float4*)cold = *(const float4*)(cst + gidx);
    float hv[4], cv[4];
#pragma unroll
    for (int j = 0; j < 4; ++j) {
      int hc = hb + j;
      float pi = gates[row * 64 + hc]      + bp[cb * 64 + hc];
      float pf = gates[row * 64 + 16 + hc] + bp[cb * 64 + 16 + hc];
      float po = gates[row * 64 + 32 + hc] + bp[cb * 64 + 32 + hc];
      float pg = gates[row * 64 + 48 + hc] + bp[cb * 64 + 48 + hc];
      float ig = 1.f / (1.f + __expf(-pi));
      float fg = 1.f / (1.f + __expf(-pf));
      float og = 1.f / (1.f + __expf(-po));
      float gg = tanhf(pg);
      float cn = fg * cold[j] + ig * gg;
      cv[j] = cn;
      hv[j] = og * tanhf(cn);
    }
    *(float4*)(cst + gidx) = *(const float4*)cv;
    {  // write h to next step's swizzled image (4 bf16 = 8 B, aligned)
      int hcg = cb * 16 + hb;
      int kc2 = hcg >> 7, kp = hcg & 127;
      unsigned int byte = ((unsigned)(row * 256 + kp * 2)) ^ ((unsigned)((row & 7) << 4));
      uint2 pk;
      pk.x = (unsigned)f2bf(hv[0]) | ((unsigned)f2bf(hv[1]) << 16);
      pk.y = (unsigned)f2bf(hv[2]) | ((unsigned)f2bf(hv[3]) << 16);
      *(uint2*)(hout + ((size_t)(mb * 8 + kc2)) * 16384 + byte) = pk;
    }
    if (t == T_DIM - 1) {
      *(float4*)(out + gidx) = *(const float4*)hv;                 // h
      *(float4*)(out + (size_t)B_DIM * HID_DIM + gidx) = *(const float4*)cv;  // c
    }
  }
}

extern "C" void kernel_launch(void* const* d_in, const int* in_sizes, int n_in,
                              void* d_out, int out_size, void* d_ws, size_t ws_size,
                              hipStream_t stream) {
  (void)in_sizes; (void)n_in; (void)out_size; (void)ws_size;
  const float* x   = (const float*)d_in[0];
  const float* Wf_ = (const float*)d_in[1];
  const float* bf_ = (const float*)d_in[2];
  const float* Wi_ = (const float*)d_in[3];
  const float* bi_ = (const float*)d_in[4];
  const float* Wo_ = (const float*)d_in[5];
  const float* bo_ = (const float*)d_in[6];
  const float* Wc_ = (const float*)d_in[7];
  const float* bc_ = (const float*)d_in[8];

  unsigned char* ws = (unsigned char*)d_ws;
  unsigned char* Wp = ws;                                   // 16 MB packed bf16 W
  float* bp = (float*)(ws + 16777216);                      // 16 KB packed f32 bias
  unsigned char* h0 = ws + 16777216 + 16384;                // 512 KB h image A
  unsigned char* h1 = h0 + 524288;                          // 512 KB h image B
  float* cst = (float*)(h1 + 524288);                       // 1 MB f32 cell state
  float* out = (float*)d_out;

  prep_pack_w<<<1024, 256, 0, stream>>>(Wi_, Wf_, Wo_, Wc_, Wp);
  prep_bias<<<16, 256, 0, stream>>>(bi_, bf_, bo_, bc_, bp);
  for (int t = 0; t < T_DIM; ++t) {
    unsigned char* hin  = (t & 1) ? h1 : h0;
    unsigned char* hout = (t & 1) ? h0 : h1;
    lstm_step<<<256, 256, 0, stream>>>(x, Wp, bp, hin, hout, cst, out, t);
  }
}